// Round 1
// baseline (1126.381 us; speedup 1.0000x reference)
//
#include <hip/hip_runtime.h>
#include <hip/hip_bf16.h>
#include <math.h>

#define Nn 1024
#define Hh 2048
#define Ee 64
#define Ii 512
#define SIi 512
#define TOPK 8
#define BMr 128
#define MAXS 16384   // 8192 pairs + 64 experts * 127 padding max

#define BN 256
#define BK 32
#define LDP 40   // padded LDS leading dim (bf16 elems)

typedef __attribute__((ext_vector_type(8))) short s16x8;
typedef __attribute__((ext_vector_type(4))) float f32x4;

// fp32x4 -> packed bf16x4 (RNE) via v_cvt_pk_bf16_f32
__device__ inline int2 cvt4(float4 v) {
    union { __hip_bfloat162 h; int i; } a, b;
    a.h = __float22bfloat162_rn(make_float2(v.x, v.y));
    b.h = __float22bfloat162_rn(make_float2(v.z, v.w));
    int2 r; r.x = a.i; r.y = b.i; return r;
}

__device__ inline float silu(float x) { return x / (1.f + expf(-x)); }

// ---------------- gating: logits (fp32), top-8, softmax, shared sigmoid gate ----
__global__ __launch_bounds__(256) void k_gate(
    const float* __restrict__ h, const float* __restrict__ gate_w,
    const float* __restrict__ sh_gate1_w,
    int* __restrict__ topi, float* __restrict__ rw,
    int* __restrict__ counts, float* __restrict__ shg)
{
    __shared__ float xs[Hh];
    __shared__ float part[256];
    __shared__ float logits[Ee];
    int n = blockIdx.x;
    const float* x = h + (long)n * Hh;
    for (int i = threadIdx.x; i < Hh / 4; i += 256)
        ((float4*)xs)[i] = ((const float4*)x)[i];
    __syncthreads();

    {
        int e = threadIdx.x & 63, q = threadIdx.x >> 6;
        const float4* w = (const float4*)(gate_w + (long)e * Hh + q * 512);
        const float4* xq = (const float4*)(xs + q * 512);
        float s = 0.f;
        for (int k = 0; k < 128; ++k) {
            float4 a = xq[k], b = w[k];
            s += a.x * b.x + a.y * b.y + a.z * b.z + a.w * b.w;
        }
        part[threadIdx.x] = s;
    }
    __syncthreads();
    if (threadIdx.x < 64)
        logits[threadIdx.x] = part[threadIdx.x] + part[threadIdx.x + 64]
                            + part[threadIdx.x + 128] + part[threadIdx.x + 192];
    __syncthreads();

    {
        float s = 0.f;
        for (int k = threadIdx.x; k < Hh; k += 256) s += xs[k] * sh_gate1_w[k];
        part[threadIdx.x] = s;
    }
    __syncthreads();
    for (int off = 128; off > 0; off >>= 1) {
        if (threadIdx.x < off) part[threadIdx.x] += part[threadIdx.x + off];
        __syncthreads();
    }

    if (threadIdx.x == 0) {
        shg[n] = 1.f / (1.f + expf(-part[0]));
        float v[TOPK]; int ix[TOPK];
        for (int kk = 0; kk < TOPK; ++kk) {
            float best = -1e30f; int bi = 0;
            for (int e = 0; e < Ee; ++e)
                if (logits[e] > best) { best = logits[e]; bi = e; }
            v[kk] = best; ix[kk] = bi; logits[bi] = -1e30f;
        }
        float mx = v[0], den = 0.f, w8[TOPK];
        for (int kk = 0; kk < TOPK; ++kk) { w8[kk] = expf(v[kk] - mx); den += w8[kk]; }
        for (int kk = 0; kk < TOPK; ++kk) {
            topi[n * TOPK + kk] = ix[kk];
            rw[n * TOPK + kk] = w8[kk] / den;
            atomicAdd(&counts[ix[kk]], 1);
        }
    }
}

// ---------------- padded prefix offsets + cursor init ----------------
__global__ void k_offsets(const int* __restrict__ counts,
                          int* __restrict__ padoff, int* __restrict__ cursor)
{
    if (threadIdx.x == 0) {
        int acc = 0;
        for (int e = 0; e < Ee; ++e) {
            padoff[e] = acc;
            acc += (counts[e] + BMr - 1) & ~(BMr - 1);
        }
        padoff[Ee] = acc;
    }
    if (threadIdx.x < Ee) cursor[threadIdx.x] = 0;
}

// ---------------- scatter pairs to per-expert slot lists ----------------
__global__ __launch_bounds__(256) void k_scatter(
    const int* __restrict__ topi, const float* __restrict__ rw,
    const int* __restrict__ padoff, int* __restrict__ cursor,
    int* __restrict__ rows, float* __restrict__ wt, int* __restrict__ slotof)
{
    int p = blockIdx.x * 256 + threadIdx.x;  // 0..8191
    int n = p >> 3;
    int e = topi[p];
    int pos = atomicAdd(&cursor[e], 1);
    int slot = padoff[e] + pos;
    rows[slot] = n;
    wt[slot] = rw[p];
    slotof[p] = slot;
}

// ---------------- fused NT GEMM: routed experts + shared expert in one grid ----
// Tile: 128(M) x 256(N) x 32(K). 512 threads, 8 waves (2M x 4N), wave = 64x64.
// WHICH 0: K=2048.  routed: A=h gathered via rows[], B=gu_w[e], C=gu_buf (slot-major)
//                   shared: A=h direct, B=sh_gate_w/sh_up_w, C=sgu[token][0..1023]
// WHICH 1: K=512.   routed: A=interb (slot-major), B=dp_w[e], C=dbuf (slot-major)
//                   shared: A=shint, B=sh_down_w, C=out = shg[token]*v
template<int WHICH>
__global__ __launch_bounds__(512, 4) void gemm_fused(
    const float* __restrict__ Ar,   // routed A (h or interb)
    const float* __restrict__ Ash,  // shared A (h or shint)
    const float* __restrict__ Wr,   // gu_w or dp_w
    const float* __restrict__ Ws0,  // sh_gate_w or sh_down_w
    const float* __restrict__ Ws1,  // sh_up_w or unused
    float* __restrict__ Cr,         // gu_buf or dbuf
    float* __restrict__ Cs,         // sgu or out
    const int* __restrict__ counts,
    const int* __restrict__ padoff,
    const int* __restrict__ rows,
    const float* __restrict__ shg)
{
    constexpr int K   = (WHICH == 0) ? Hh : Ii;      // 2048 / 512 (== lda == ldb)
    constexpr int NT  = (WHICH == 0) ? 4 : 8;        // routed ntiles over N
    constexpr int NR  = Ee * NT;                     // routed x-blocks: 256 / 512
    constexpr int LDC = (WHICH == 0) ? 1024 : Hh;    // C leading dim (both paths)

    __shared__ short Asm[BMr * LDP];
    __shared__ short Bsm[BN * LDP];
    __shared__ int   arow[BMr];

    int bx = blockIdx.x, my = blockIdx.y;
    bool routed = bx < NR;
    const float* Ab;
    const float* Bb;
    int m0, n0;

    if (routed) {
        int e = bx / NT, nt = bx % NT;
        int Me = counts[e];
        if (my * BMr >= Me) return;
        m0 = padoff[e] + my * BMr;
        n0 = nt * BN;
        Ab = Ar;
        Bb = Wr + (size_t)e * ((size_t)((WHICH == 0) ? 1024 : Hh) * K) + (size_t)n0 * K;
    } else {
        int s = bx - NR;
        m0 = my * BMr;          // token block
        n0 = s * BN;
        Ab = Ash;
        if (WHICH == 0) Bb = (s < 2 ? Ws0 : Ws1) + (size_t)((s & 1) * BN) * K;
        else            Bb = Ws0 + (size_t)n0 * K;
    }

    if (threadIdx.x < BMr) {
        int r;
        if (WHICH == 0 && routed) r = rows[m0 + threadIdx.x];
        else                      r = m0 + threadIdx.x;
        arow[threadIdx.x] = r;
    }
    __syncthreads();

    f32x4 acc[4][4];
    #pragma unroll
    for (int cm = 0; cm < 4; ++cm)
        #pragma unroll
        for (int cn = 0; cn < 4; ++cn)
            acc[cm][cn] = (f32x4){0.f, 0.f, 0.f, 0.f};

    int lane = threadIdx.x & 63;
    int wave = threadIdx.x >> 6;
    int wm = wave >> 2, wn = wave & 3;
    int fr = lane & 15, quad = lane >> 4;

    float4 av[2], bv[4];

    auto issue = [&](int k0) {
        #pragma unroll
        for (int it = 0; it < 2; ++it) {          // A: 128 rows x 8 float4
            int s = threadIdx.x + it * 512;
            int m = s >> 3, kq = s & 7;
            int r = arow[m];
            if (WHICH == 0 && r < 0) av[it] = make_float4(0.f, 0.f, 0.f, 0.f);
            else av[it] = *((const float4*)(Ab + (size_t)r * K + k0 + kq * 4));
        }
        #pragma unroll
        for (int it = 0; it < 4; ++it) {          // B: 256 rows x 8 float4
            int s = threadIdx.x + it * 512;
            int nn = s >> 3, kq = s & 7;
            bv[it] = *((const float4*)(Bb + (size_t)nn * K + k0 + kq * 4));
        }
    };

    issue(0);

    for (int k0 = 0; k0 < K; k0 += BK) {
        __syncthreads();   // everyone done reading LDS from previous iter
        #pragma unroll
        for (int it = 0; it < 2; ++it) {
            int s = threadIdx.x + it * 512;
            int m = s >> 3, kq = s & 7;
            *(int2*)(&Asm[m * LDP + kq * 4]) = cvt4(av[it]);
        }
        #pragma unroll
        for (int it = 0; it < 4; ++it) {
            int s = threadIdx.x + it * 512;
            int nn = s >> 3, kq = s & 7;
            *(int2*)(&Bsm[nn * LDP + kq * 4]) = cvt4(bv[it]);
        }
        __syncthreads();   // LDS tiles visible

        if (k0 + BK < K) issue(k0 + BK);   // prefetch; waited at next store

        s16x8 bf[4];
        #pragma unroll
        for (int cn = 0; cn < 4; ++cn)
            bf[cn] = *(const s16x8*)(&Bsm[(wn * 64 + cn * 16 + fr) * LDP + quad * 8]);
        #pragma unroll
        for (int cm = 0; cm < 4; ++cm) {
            s16x8 af = *(const s16x8*)(&Asm[(wm * 64 + cm * 16 + fr) * LDP + quad * 8]);
            #pragma unroll
            for (int cn = 0; cn < 4; ++cn)
                acc[cm][cn] = __builtin_amdgcn_mfma_f32_16x16x32_bf16(
                    af, bf[cn], acc[cm][cn], 0, 0, 0);
        }
    }

    // epilogue: C/D layout col = lane&15, row = quad*4 + reg
    #pragma unroll
    for (int cm = 0; cm < 4; ++cm) {
        #pragma unroll
        for (int cn = 0; cn < 4; ++cn) {
            int col = n0 + wn * 64 + cn * 16 + fr;
            #pragma unroll
            for (int r2 = 0; r2 < 4; ++r2) {
                int row = m0 + wm * 64 + cm * 16 + quad * 4 + r2;
                float v = acc[cm][cn][r2];
                if (routed)          Cr[(size_t)row * LDC + col] = v;
                else if (WHICH == 0) Cs[(size_t)row * 1024 + col] = v;
                else                 Cs[(size_t)row * Hh + col] = shg[row] * v;
            }
        }
    }
}

// ---------------- routed inter = silu(g)*u * routing_weight ----------------
__global__ __launch_bounds__(256) void k_inter(
    const float* __restrict__ gu, const int* __restrict__ rows,
    const float* __restrict__ wt, float* __restrict__ inter)
{
    int i = blockIdx.x * 256 + threadIdx.x;   // over MAXS*512
    int slot = i >> 9, ii = i & 511;
    float v = 0.f;
    if (rows[slot] >= 0) {
        float g = gu[(long)slot * 1024 + ii];
        float u = gu[(long)slot * 1024 + 512 + ii];
        v = silu(g) * u * wt[slot];
    }
    inter[(long)slot * 512 + ii] = v;
}

// ---------------- shared inter = silu(g)*u (combined sgu layout) ----------------
__global__ __launch_bounds__(256) void k_sh_inter(
    const float* __restrict__ sgu, float* __restrict__ si)
{
    int i = blockIdx.x * 256 + threadIdx.x;   // Nn*SIi
    int t = i >> 9, ii = i & 511;
    float g = sgu[(long)t * 1024 + ii];
    float u = sgu[(long)t * 1024 + 512 + ii];
    si[i] = silu(g) * u;
}

// ---------------- final: out[t] = shared_part[t] + sum_k dbuf[slot(t,k)] ----
__global__ __launch_bounds__(256) void k_final(
    const float* __restrict__ dbuf, const int* __restrict__ slotof,
    float* __restrict__ out)
{
    int t = blockIdx.x;
    __shared__ int sl[TOPK];
    if (threadIdx.x < TOPK) sl[threadIdx.x] = slotof[t * TOPK + threadIdx.x];
    __syncthreads();
    #pragma unroll
    for (int rep = 0; rep < 2; ++rep) {
        int j = threadIdx.x * 4 + rep * 1024;
        float4 acc = *(float4*)&out[(long)t * Hh + j];   // shared-down value
        #pragma unroll
        for (int k = 0; k < TOPK; ++k) {
            float4 v = *(const float4*)&dbuf[(long)sl[k] * Hh + j];
            acc.x += v.x; acc.y += v.y; acc.z += v.z; acc.w += v.w;
        }
        *(float4*)&out[(long)t * Hh + j] = acc;
    }
}

extern "C" void kernel_launch(void* const* d_in, const int* in_sizes, int n_in,
                              void* d_out, int out_size, void* d_ws, size_t ws_size,
                              hipStream_t stream) {
    const float* h          = (const float*)d_in[0];
    const float* gate_w     = (const float*)d_in[1];
    const float* gu_w       = (const float*)d_in[2];
    const float* dp_w       = (const float*)d_in[3];
    const float* sh_gate_w  = (const float*)d_in[4];
    const float* sh_up_w    = (const float*)d_in[5];
    const float* sh_down_w  = (const float*)d_in[6];
    const float* sh_gate1_w = (const float*)d_in[7];
    float* out = (float*)d_out;
    (void)ws_size; (void)in_sizes; (void)n_in; (void)out_size;

    char* ws = (char*)d_ws;
    size_t off = 0;
    auto alloc = [&](size_t bytes) {
        void* p = ws + off; off += (bytes + 255) & ~(size_t)255; return p;
    };
    int*   topi    = (int*)  alloc(Nn * TOPK * 4);
    float* rw      = (float*)alloc(Nn * TOPK * 4);
    int*   counts  = (int*)  alloc(Ee * 4);
    int*   padoff  = (int*)  alloc((Ee + 1) * 4);
    int*   cursor  = (int*)  alloc(Ee * 4);
    float* shg     = (float*)alloc(Nn * 4);
    int*   rows    = (int*)  alloc(MAXS * 4);
    float* wt      = (float*)alloc(MAXS * 4);
    int*   slotof  = (int*)  alloc(Nn * TOPK * 4);
    float* gu_buf  = (float*)alloc((size_t)MAXS * 1024 * 4);
    float* interb  = (float*)alloc((size_t)MAXS * 512 * 4);
    float* dbuf    = (float*)alloc((size_t)MAXS * Hh * 4);
    float* sgu     = (float*)alloc((size_t)Nn * 1024 * 4);
    float* shint   = (float*)alloc((size_t)Nn * SIi * 4);

    hipMemsetAsync(counts, 0, Ee * 4, stream);
    hipMemsetAsync(rows, 0xFF, MAXS * 4, stream);   // -1 sentinel

    k_gate<<<Nn, 256, 0, stream>>>(h, gate_w, sh_gate1_w, topi, rw, counts, shg);
    k_offsets<<<1, 64, 0, stream>>>(counts, padoff, cursor);
    k_scatter<<<Nn * TOPK / 256, 256, 0, stream>>>(topi, rw, padoff, cursor,
                                                   rows, wt, slotof);

    // routed gu (N=1024 -> 4 ntiles) + shared gate/up (4 extra x-blocks)
    gemm_fused<0><<<dim3(Ee * 4 + 4, 8), 512, 0, stream>>>(
        h, h, gu_w, sh_gate_w, sh_up_w, gu_buf, sgu,
        counts, padoff, rows, nullptr);

    k_inter<<<MAXS * 2, 256, 0, stream>>>(gu_buf, rows, wt, interb);
    k_sh_inter<<<Nn * SIi / 256, 256, 0, stream>>>(sgu, shint);

    // routed down (N=2048 -> 8 ntiles) -> dbuf; shared down -> out (scaled store)
    gemm_fused<1><<<dim3(Ee * 8 + 8, 8), 512, 0, stream>>>(
        interb, shint, dp_w, sh_down_w, nullptr, dbuf, out,
        counts, padoff, rows, shg);

    // out[t] += sum of its 8 expert slots
    k_final<<<Nn, 256, 0, stream>>>(dbuf, slotof, out);
}